// Round 1
// baseline (63.048 us; speedup 1.0000x reference)
//
#include <hip/hip_runtime.h>
#include <hip/hip_bf16.h>
#include <math.h>

#define COUPLING 0.12f
#define EPSV 1e-8f
#define SCALE2L2E 2.8853900817779268f   // 2*log2(e): folds tanh's 2x and exp->exp2

typedef __attribute__((ext_vector_type(8))) short bf16x8;
typedef __attribute__((ext_vector_type(4))) float f32x4;

// tanh(x) from y = 2x*log2(e):  tanh = 1 - 2/(1+2^y). Inf-safe both ways.
__device__ __forceinline__ float tanh_from_e2(float y) {
    float e = __builtin_amdgcn_exp2f(y);
    float r = __builtin_amdgcn_rcpf(1.0f + e);
    return fmaf(-2.0f, r, 1.0f);
}
__device__ __forceinline__ float tanh_fast(float x) {
    return tanh_from_e2(SCALE2L2E * x);
}
// sigma(y) = 1/(1+2^y); tanh = 1 - 2*sigma. Accumulate sigma, fix up with
// valid-row count N at reduction: sum(tanh) = N - 2*sum(sigma). Saves one
// fma per accumulated element vs tanh_from_e2 (32 fma/tile).
__device__ __forceinline__ float sig_e2(float y) {
    float e = __builtin_amdgcn_exp2f(y);
    return __builtin_amdgcn_rcpf(1.0f + e);
}

__device__ __forceinline__ short f2bf(float f) {
    __hip_bfloat16 h = __float2bfloat16(f);
    return __builtin_bit_cast(short, h);
}

// Pre-pass (1 block, 128 threads): per output channel oh,
//   cpre[oh] = SCALE * (heads_b[oh] + cand . heads_w[oh][0:32])   (f32)
//   wbf[oh][k] = bf16(SCALE * heads_w[oh][32+k]), k in [0,32)
__global__ __launch_bounds__(128) void phot_prep(
    const float* __restrict__ heads_w, const float* __restrict__ heads_b,
    const float* __restrict__ cand, float* __restrict__ cpre,
    short* __restrict__ wbf)
{
    const int oh = threadIdx.x;               // 0..127
    const float* wr = heads_w + (size_t)oh * 64;
    float s0 = heads_b[oh], s1 = 0.f, s2 = 0.f, s3 = 0.f;
    #pragma unroll
    for (int k = 0; k < 32; k += 4) {
        s0 = fmaf(wr[k+0], cand[k+0], s0);
        s1 = fmaf(wr[k+1], cand[k+1], s1);
        s2 = fmaf(wr[k+2], cand[k+2], s2);
        s3 = fmaf(wr[k+3], cand[k+3], s3);
    }
    cpre[oh] = SCALE2L2E * ((s0 + s1) + (s2 + s3));
    short* wo = wbf + (size_t)oh * 32;
    #pragma unroll
    for (int k = 0; k < 32; ++k) wo[k] = f2bf(SCALE2L2E * wr[32 + k]);
}

// Main: per 16-row tile one wave does 8x mfma_f32_16x16x32_bf16 (128 output
// channels), sigma on each f32 acc elem, running per-lane sums. All fragments
// and accumulators are NAMED registers (no arrays -> no scratch).
// C/D layout: col=lane&15, row=(lane>>4)*4+reg (m89-verified).
// Round-4: grid 1024->2048 (8 blocks/CU; latency-bound per Little's law:
// 4 waves/SIMD * 2KB in-flight gave exactly the measured 1.5 TB/s), and
// accumulate sigma instead of tanh (count fixed up analytically post-loop,
// zero extra loop-carried registers).
__global__ __launch_bounds__(256, 4) void phot_main(
    const float* __restrict__ z_past,   // [P][32] fp32
    const short* __restrict__ wbf,      // [128][32] bf16, pre-scaled
    const float* __restrict__ cpre_g,   // [128] f32, pre-scaled
    float* __restrict__ partials,       // [nblk][128]
    int P, int NW)                      // NW = total wave count
{
    __shared__ float wacc[4][128];

    const int tid  = threadIdx.x;
    const int lane = tid & 63;
    const int wv   = tid >> 6;
    const int col  = lane & 15;   // A-row / B-col / C-col
    const int kg   = lane >> 4;   // k-group (k = kg*8 + e)

    // B fragments + per-channel constants (named)
    #define LDB(G) \
        const bf16x8 bfrag##G = *(const bf16x8*)(wbf + (size_t)((G)*16 + col) * 32 + kg * 8); \
        const float cp##G = cpre_g[(G)*16 + col];
    LDB(0) LDB(1) LDB(2) LDB(3) LDB(4) LDB(5) LDB(6) LDB(7)
    #undef LDB

    f32x4 acc0 = {0,0,0,0}, acc1 = {0,0,0,0}, acc2 = {0,0,0,0}, acc3 = {0,0,0,0},
          acc4 = {0,0,0,0}, acc5 = {0,0,0,0}, acc6 = {0,0,0,0}, acc7 = {0,0,0,0};

    const int T  = (P + 15) >> 4;             // 16-row tiles
    const int gw = blockIdx.x * 4 + wv;       // global wave id

    int t = gw;
    if (t < T) {
        int row0 = t * 16 + col; if (row0 > P - 1) row0 = P - 1;
        const float* zr0 = z_past + (size_t)row0 * 32 + kg * 8;
        float4 c_lo = *(const float4*)zr0;
        float4 c_hi = *(const float4*)(zr0 + 4);

        for (;;) {
            const int tn = t + NW;
            const bool more = (tn < T);
            float4 n_lo, n_hi;
            if (more) {
                int row1 = tn * 16 + col; if (row1 > P - 1) row1 = P - 1;
                const float* zr1 = z_past + (size_t)row1 * 32 + kg * 8;
                n_lo = *(const float4*)zr1;
                n_hi = *(const float4*)(zr1 + 4);
            }

            bf16x8 a;
            a[0] = f2bf(c_lo.x); a[1] = f2bf(c_lo.y);
            a[2] = f2bf(c_lo.z); a[3] = f2bf(c_lo.w);
            a[4] = f2bf(c_hi.x); a[5] = f2bf(c_hi.y);
            a[6] = f2bf(c_hi.z); a[7] = f2bf(c_hi.w);

            const int base = t * 16;
            if (base + 16 <= P) {
                #define STEP(G) { \
                    f32x4 c = {cp##G, cp##G, cp##G, cp##G}; \
                    f32x4 d = __builtin_amdgcn_mfma_f32_16x16x32_bf16(a, bfrag##G, c, 0, 0, 0); \
                    acc##G[0] += sig_e2(d[0]); \
                    acc##G[1] += sig_e2(d[1]); \
                    acc##G[2] += sig_e2(d[2]); \
                    acc##G[3] += sig_e2(d[3]); }
                STEP(0) STEP(1) STEP(2) STEP(3) STEP(4) STEP(5) STEP(6) STEP(7)
                #undef STEP
            } else {
                const int r0 = base + kg * 4;
                #define STEPT(G) { \
                    f32x4 c = {cp##G, cp##G, cp##G, cp##G}; \
                    f32x4 d = __builtin_amdgcn_mfma_f32_16x16x32_bf16(a, bfrag##G, c, 0, 0, 0); \
                    if (r0 + 0 < P) acc##G[0] += sig_e2(d[0]); \
                    if (r0 + 1 < P) acc##G[1] += sig_e2(d[1]); \
                    if (r0 + 2 < P) acc##G[2] += sig_e2(d[2]); \
                    if (r0 + 3 < P) acc##G[3] += sig_e2(d[3]); }
                STEPT(0) STEPT(1) STEPT(2) STEPT(3) STEPT(4) STEPT(5) STEPT(6) STEPT(7)
                #undef STEPT
            }

            if (!more) break;
            c_lo = n_lo; c_hi = n_hi; t = tn;
        }
    }

    // Per-lane valid-row count, recomputed analytically (no loop-carried regs):
    // each acc element e accumulated one row per processed tile; only the last
    // tile (t_last) can be partial. nsum = 4*(niters-1) + clamp(P - r0_last, 0, 4).
    float nsum = 0.0f;
    if (gw < T) {
        const int niters = (T - 1 - gw) / NW + 1;
        const int r0l = (gw + (niters - 1) * NW) * 16 + kg * 4;
        int nv = P - r0l; if (nv < 0) nv = 0; if (nv > 4) nv = 4;
        nsum = (float)(4 * (niters - 1) + nv);
    }

    // reduce: sum(tanh) = nsum - 2*sum(sigma); fold 4 row-regs, then the
    // 4 k-groups (lanes 16 apart)
    #define RED(G) { \
        float s = nsum - 2.0f * ((acc##G[0] + acc##G[1]) + (acc##G[2] + acc##G[3])); \
        s += __shfl_xor(s, 16, 64); \
        s += __shfl_xor(s, 32, 64); \
        if (lane < 16) wacc[wv][(G) * 16 + lane] = s; }
    RED(0) RED(1) RED(2) RED(3) RED(4) RED(5) RED(6) RED(7)
    #undef RED

    __syncthreads();
    if (tid < 128) {
        partials[(size_t)blockIdx.x * 128 + tid] =
            (wacc[0][tid] + wacc[1][tid]) + (wacc[2][tid] + wacc[3][tid]);
    }
}

// Finalize (validated in rounds 1-2).
__global__ __launch_bounds__(1024) void phot_finalize(
    const float* __restrict__ partials, int nblk, int P,
    const float* __restrict__ out_w,      // [32][128]
    const float* __restrict__ out_b,      // [32]
    const float* __restrict__ rel_bias,   // [129][2]
    const float* __restrict__ cand,       // [32]
    const float* __restrict__ norm_scale, // [1]
    const int* __restrict__ posp,         // [1]
    float* __restrict__ out)              // [32]
{
    __shared__ float  sh[1024];
    __shared__ float  cm[128];
    __shared__ float  outv[32];
    __shared__ double db[512];
    __shared__ float  bm[2];

    const int t  = threadIdx.x;
    const int oh = t & 127;
    const int sl = t >> 7;          // 0..7 slices over blocks

    const int seg = nblk >> 3;      // nblk is a multiple of 8
    const int b0  = sl * seg;
    float a0=0.f,a1=0.f,a2=0.f,a3=0.f,a4=0.f,a5=0.f,a6=0.f,a7=0.f;
    int i = 0;
    for (; i + 8 <= seg; i += 8) {
        const float* pp = partials + (size_t)(b0 + i) * 128 + oh;
        a0 += pp[0*128]; a1 += pp[1*128]; a2 += pp[2*128]; a3 += pp[3*128];
        a4 += pp[4*128]; a5 += pp[5*128]; a6 += pp[6*128]; a7 += pp[7*128];
    }
    for (; i < seg; ++i) a0 += partials[(size_t)(b0 + i) * 128 + oh];
    sh[t] = ((a0+a1)+(a2+a3)) + ((a4+a5)+(a6+a7));
    __syncthreads();

    if (t < 128) {
        float s = 0.0f;
        #pragma unroll
        for (int s2 = 0; s2 < 8; ++s2) s += sh[t + 128*s2];
        cm[t] = s / (float)P;
    }

    // rel-bias mean, closed form per bin; idx(p)=clamp(a+p,0,128), a=pos-P+64
    if (t < 512) {
        const int c = t >> 8, j = t & 255;
        double v = 0.0;
        if (j <= 128) {
            const long long pos = (long long)(*posp);
            const long long a = pos - (long long)P + 64;
            double cnt;
            if (j == 0) {
                long long hi = -a; if (hi > (long long)P - 1) hi = (long long)P - 1;
                cnt = (hi >= 0) ? (double)(hi + 1) : 0.0;
            } else if (j == 128) {
                long long lo = 128 - a; if (lo < 0) lo = 0;
                cnt = (lo <= (long long)P - 1) ? (double)((long long)P - lo) : 0.0;
            } else {
                long long p = (long long)j - a;
                cnt = (p >= 0 && p < (long long)P) ? 1.0 : 0.0;
            }
            v = cnt * (double)rel_bias[2*j + c];
        }
        db[t] = v;
    }
    __syncthreads();
    #pragma unroll
    for (int s = 128; s >= 1; s >>= 1) {
        if (t < 512 && (t & 255) < s) db[t] += db[t + s];
        __syncthreads();
    }
    if (t < 2) bm[t] = (float)(db[t << 8] / (double)P);
    __syncthreads();

    if (t < 32) {
        const float* wr = out_w + t * 128;
        float o0 = out_b[t], o1 = 0.f, o2 = 0.f, o3 = 0.f;
        #pragma unroll
        for (int j = 0; j < 128; j += 4) {
            o0 = fmaf(wr[j+0], cm[j+0], o0);
            o1 = fmaf(wr[j+1], cm[j+1], o1);
            o2 = fmaf(wr[j+2], cm[j+2], o2);
            o3 = fmaf(wr[j+3], cm[j+3], o3);
        }
        outv[t] = (o0+o1) + (o2+o3);
    }
    __syncthreads();

    if (t < 32) {
        float zt = tanh_fast(cand[t] + COUPLING * (outv[t] + bm[t & 1]));
        float other = __shfl_xor(zt, 1, 64);
        float m = fmaf(zt, zt, other * other);
        #pragma unroll
        for (int off = 2; off < 32; off <<= 1) m = fmaxf(m, __shfl_xor(m, off, 64));
        float scale = norm_scale[0] / sqrtf(m + EPSV);
        out[t] = (m > 0.0f) ? zt * scale : zt;
    }
}

extern "C" void kernel_launch(void* const* d_in, const int* in_sizes, int n_in,
                              void* d_out, int out_size, void* d_ws, size_t ws_size,
                              hipStream_t stream)
{
    const float* cand       = (const float*)d_in[0];
    const float* z_past     = (const float*)d_in[1];
    const float* heads_w    = (const float*)d_in[2];
    const float* heads_b    = (const float*)d_in[3];
    const float* out_w      = (const float*)d_in[4];
    const float* out_b      = (const float*)d_in[5];
    const float* rel_bias   = (const float*)d_in[6];
    const float* norm_scale = (const float*)d_in[7];
    const int*   posp       = (const int*)d_in[8];

    const int P = in_sizes[1] / 32;

    int nblk = 2048;                              // 8 blocks/CU, 32 waves/CU
    size_t need = ((size_t)nblk * 128 + 128) * sizeof(float) + 128 * 32 * sizeof(short);
    if (need > ws_size) {
        nblk = (int)((ws_size - 128 * sizeof(float) - 128 * 32 * sizeof(short))
                     / (128 * sizeof(float)));
        nblk &= ~7;
        if (nblk < 8) nblk = 8;
    }
    float* partials = (float*)d_ws;
    float* cpre     = partials + (size_t)nblk * 128;
    short* wbf      = (short*)(cpre + 128);

    phot_prep<<<1, 128, 0, stream>>>(heads_w, heads_b, cand, cpre, wbf);
    phot_main<<<nblk, 256, 0, stream>>>(z_past, wbf, cpre, partials, P, nblk * 4);
    phot_finalize<<<1, 1024, 0, stream>>>(partials, nblk, P, out_w, out_b,
                                          rel_bias, cand, norm_scale, posp,
                                          (float*)d_out);
}

// Round 2
// 45.670 us; speedup vs baseline: 1.3805x; 1.3805x over previous
//
#include <hip/hip_runtime.h>
#include <hip/hip_bf16.h>
#include <math.h>

#define COUPLING 0.12f
#define EPSV 1e-8f
#define SCALE2L2E 2.8853900817779268f   // 2*log2(e): folds tanh's 2x and exp->exp2

typedef __attribute__((ext_vector_type(8))) short bf16x8;
typedef __attribute__((ext_vector_type(4))) float f32x4;

typedef __attribute__((address_space(1))) const float global_cfloat;
typedef __attribute__((address_space(3))) float lds_float;

// tanh(x) from y = 2x*log2(e):  tanh = 1 - 2/(1+2^y). Inf-safe both ways.
__device__ __forceinline__ float tanh_from_e2(float y) {
    float e = __builtin_amdgcn_exp2f(y);
    float r = __builtin_amdgcn_rcpf(1.0f + e);
    return fmaf(-2.0f, r, 1.0f);
}
__device__ __forceinline__ float tanh_fast(float x) {
    return tanh_from_e2(SCALE2L2E * x);
}
// sigma(y) = 1/(1+2^y); tanh = 1 - 2*sigma. Accumulate sigma, fix up with
// valid-row count N at reduction: sum(tanh) = N - 2*sum(sigma).
__device__ __forceinline__ float sig_e2(float y) {
    float e = __builtin_amdgcn_exp2f(y);
    return __builtin_amdgcn_rcpf(1.0f + e);
}

__device__ __forceinline__ short f2bf(float f) {
    __hip_bfloat16 h = __float2bfloat16(f);
    return __builtin_bit_cast(short, h);
}

// Pre-pass (1 block, 128 threads): per output channel oh,
//   cpre[oh] = SCALE * (heads_b[oh] + cand . heads_w[oh][0:32])   (f32)
//   wbf[oh][k] = bf16(SCALE * heads_w[oh][32+k]), k in [0,32)
__global__ __launch_bounds__(128) void phot_prep(
    const float* __restrict__ heads_w, const float* __restrict__ heads_b,
    const float* __restrict__ cand, float* __restrict__ cpre,
    short* __restrict__ wbf)
{
    const int oh = threadIdx.x;               // 0..127
    const float* wr = heads_w + (size_t)oh * 64;
    float s0 = heads_b[oh], s1 = 0.f, s2 = 0.f, s3 = 0.f;
    #pragma unroll
    for (int k = 0; k < 32; k += 4) {
        s0 = fmaf(wr[k+0], cand[k+0], s0);
        s1 = fmaf(wr[k+1], cand[k+1], s1);
        s2 = fmaf(wr[k+2], cand[k+2], s2);
        s3 = fmaf(wr[k+3], cand[k+3], s3);
    }
    cpre[oh] = SCALE2L2E * ((s0 + s1) + (s2 + s3));
    short* wo = wbf + (size_t)oh * 32;
    #pragma unroll
    for (int k = 0; k < 32; ++k) wo[k] = f2bf(SCALE2L2E * wr[32 + k]);
}

// Main. Round-5 structure:
//  - nblk back to 1024 (round-1 A/B: occupancy is reg-capped at 4 waves/EU;
//    2048 blocks only doubled per-block overhead).
//  - z_past staging via global_load_lds width-16 into wave-private
//    double-buffered LDS (2x2KB per wave). Removes the 16 float4-staging
//    VGPRs (the largest live-across-MFMA values) -> per-thread hot state
//    ~95 regs, fits the 128 unified-file budget -> no scratch spill
//    (round 0/1: 21.5 KB/block WRITE_SIZE == prologue spill, reloaded
//    inside the loop == the 70% stall).
//  - LDS tile swizzle: logical byte x within the 2KB tile lives at LDS byte
//    x ^ ((row&7)<<4) (row = x>>7). global_load_lds writes LDS linearly, so
//    the involution is applied to the per-lane GLOBAL source address on the
//    write side and to the ds_read_b128 address on the read side
//    (both-sides-or-neither). Makes the 16-row column read conflict-free.
//  - No __syncthreads in the loop (wave-private buffers); counted
//    s_waitcnt vmcnt(2) keeps next tile's loads in flight across compute.
// C/D layout: col=lane&15, row=(lane>>4)*4+reg (m89-verified).
__global__ __launch_bounds__(256, 4) void phot_main(
    const float* __restrict__ z_past,   // [P][32] fp32
    const short* __restrict__ wbf,      // [128][32] bf16, pre-scaled
    const float* __restrict__ cpre_g,   // [128] f32, pre-scaled
    float* __restrict__ partials,       // [nblk][128]
    int P, int NW)                      // NW = total wave count
{
    __shared__ float wacc[4][128];
    __shared__ __align__(16) float zbuf[4][2][512];   // per-wave dbuf, 2KB each

    const int tid  = threadIdx.x;
    const int lane = tid & 63;
    const int wv   = tid >> 6;
    const int col  = lane & 15;   // A-row / B-col / C-col
    const int kg   = lane >> 4;   // k-group (k = kg*8 + e)

    // B fragments + per-channel constants (named registers, loop-invariant)
    #define LDB(G) \
        const bf16x8 bfrag##G = *(const bf16x8*)(wbf + (size_t)((G)*16 + col) * 32 + kg * 8); \
        const float cp##G = cpre_g[(G)*16 + col];
    LDB(0) LDB(1) LDB(2) LDB(3) LDB(4) LDB(5) LDB(6) LDB(7)
    #undef LDB

    f32x4 acc0 = {0,0,0,0}, acc1 = {0,0,0,0}, acc2 = {0,0,0,0}, acc3 = {0,0,0,0},
          acc4 = {0,0,0,0}, acc5 = {0,0,0,0}, acc6 = {0,0,0,0}, acc7 = {0,0,0,0};

    const int Tf = P >> 4;                    // full 16-row tiles
    const int T  = (P + 15) >> 4;             // total tiles (incl. partial)
    const int gw = blockIdx.x * 4 + wv;       // global wave id

    // Pre-swizzled per-lane source offset (floats) within a 2KB tile:
    // lane l stages LDS bytes [16l,16l+16) (+1024 for the 2nd instr); the
    // content must be global byte S(y) = y ^ ((row&7)<<4), row = y>>7.
    const int lrow = lane >> 3;               // 0..7
    const int lsw  = lrow * 32 + ((lane & 7) ^ lrow) * 4;   // floats

    // STAGE(tile) -> zbuf[wv][b]: 2x global_load_lds_dwordx4, LDS linear dest,
    // swizzled global source.
    #define STAGE(b, tt) { \
        const float* g0 = z_past + (size_t)(tt) * 512 + lsw; \
        __builtin_amdgcn_global_load_lds((global_cfloat*)g0, \
            (lds_float*)&zbuf[wv][b][0], 16, 0, 0); \
        __builtin_amdgcn_global_load_lds((global_cfloat*)(g0 + 256), \
            (lds_float*)&zbuf[wv][b][256], 16, 0, 0); }

    int t = gw;
    int cur = 0;
    if (t < T) {
        if (t < Tf) STAGE(0, t);

        for (;;) {
            const int tn = t + NW;
            const bool more    = (tn < T);
            const bool tn_full = (tn < Tf);
            if (more && tn_full) STAGE(cur ^ 1, tn);

            if (t < Tf) {
                // wait for THIS tile's 2 loads; leave next tile's in flight
                if (more && tn_full) asm volatile("s_waitcnt vmcnt(2)" ::: "memory");
                else                 asm volatile("s_waitcnt vmcnt(0)" ::: "memory");

                const char* lb  = (const char*)&zbuf[wv][cur][0];
                const int   swz = (col & 7) << 4;
                const int   rb  = col * 128;
                f32x4 lo = *(const f32x4*)(lb + rb + ((kg * 32)      ^ swz));
                f32x4 hi = *(const f32x4*)(lb + rb + ((kg * 32 + 16) ^ swz));

                bf16x8 a;
                a[0] = f2bf(lo[0]); a[1] = f2bf(lo[1]);
                a[2] = f2bf(lo[2]); a[3] = f2bf(lo[3]);
                a[4] = f2bf(hi[0]); a[5] = f2bf(hi[1]);
                a[6] = f2bf(hi[2]); a[7] = f2bf(hi[3]);

                #define STEP(G) { \
                    f32x4 c = {cp##G, cp##G, cp##G, cp##G}; \
                    f32x4 d = __builtin_amdgcn_mfma_f32_16x16x32_bf16(a, bfrag##G, c, 0, 0, 0); \
                    acc##G[0] += sig_e2(d[0]); \
                    acc##G[1] += sig_e2(d[1]); \
                    acc##G[2] += sig_e2(d[2]); \
                    acc##G[3] += sig_e2(d[3]); }
                STEP(0) STEP(1) STEP(2) STEP(3) STEP(4) STEP(5) STEP(6) STEP(7)
                #undef STEP
            } else {
                // partial tail tile (cold; only when P % 16 != 0): direct
                // clamped register loads, no staging was issued for it.
                asm volatile("s_waitcnt vmcnt(0)" ::: "memory");
                int row0 = t * 16 + col; if (row0 > P - 1) row0 = P - 1;
                const float* zr = z_past + (size_t)row0 * 32 + kg * 8;
                float4 c_lo = *(const float4*)zr;
                float4 c_hi = *(const float4*)(zr + 4);
                bf16x8 a;
                a[0] = f2bf(c_lo.x); a[1] = f2bf(c_lo.y);
                a[2] = f2bf(c_lo.z); a[3] = f2bf(c_lo.w);
                a[4] = f2bf(c_hi.x); a[5] = f2bf(c_hi.y);
                a[6] = f2bf(c_hi.z); a[7] = f2bf(c_hi.w);
                const int r0 = t * 16 + kg * 4;
                #define STEPT(G) { \
                    f32x4 c = {cp##G, cp##G, cp##G, cp##G}; \
                    f32x4 d = __builtin_amdgcn_mfma_f32_16x16x32_bf16(a, bfrag##G, c, 0, 0, 0); \
                    if (r0 + 0 < P) acc##G[0] += sig_e2(d[0]); \
                    if (r0 + 1 < P) acc##G[1] += sig_e2(d[1]); \
                    if (r0 + 2 < P) acc##G[2] += sig_e2(d[2]); \
                    if (r0 + 3 < P) acc##G[3] += sig_e2(d[3]); }
                STEPT(0) STEPT(1) STEPT(2) STEPT(3) STEPT(4) STEPT(5) STEPT(6) STEPT(7)
                #undef STEPT
            }

            if (!more) break;
            t = tn; cur ^= 1;
        }
    }
    #undef STAGE

    // Per-lane valid-row count, recomputed analytically (no loop-carried regs).
    float nsum = 0.0f;
    if (gw < T) {
        const int niters = (T - 1 - gw) / NW + 1;
        const int r0l = (gw + (niters - 1) * NW) * 16 + kg * 4;
        int nv = P - r0l; if (nv < 0) nv = 0; if (nv > 4) nv = 4;
        nsum = (float)(4 * (niters - 1) + nv);
    }

    // reduce: sum(tanh) = nsum - 2*sum(sigma); fold 4 row-regs, then the
    // 4 k-groups (lanes 16 apart)
    #define RED(G) { \
        float s = nsum - 2.0f * ((acc##G[0] + acc##G[1]) + (acc##G[2] + acc##G[3])); \
        s += __shfl_xor(s, 16, 64); \
        s += __shfl_xor(s, 32, 64); \
        if (lane < 16) wacc[wv][(G) * 16 + lane] = s; }
    RED(0) RED(1) RED(2) RED(3) RED(4) RED(5) RED(6) RED(7)
    #undef RED

    __syncthreads();
    if (tid < 128) {
        partials[(size_t)blockIdx.x * 128 + tid] =
            (wacc[0][tid] + wacc[1][tid]) + (wacc[2][tid] + wacc[3][tid]);
    }
}

// Finalize (validated in rounds 1-2).
__global__ __launch_bounds__(1024) void phot_finalize(
    const float* __restrict__ partials, int nblk, int P,
    const float* __restrict__ out_w,      // [32][128]
    const float* __restrict__ out_b,      // [32]
    const float* __restrict__ rel_bias,   // [129][2]
    const float* __restrict__ cand,       // [32]
    const float* __restrict__ norm_scale, // [1]
    const int* __restrict__ posp,         // [1]
    float* __restrict__ out)              // [32]
{
    __shared__ float  sh[1024];
    __shared__ float  cm[128];
    __shared__ float  outv[32];
    __shared__ double db[512];
    __shared__ float  bm[2];

    const int t  = threadIdx.x;
    const int oh = t & 127;
    const int sl = t >> 7;          // 0..7 slices over blocks

    const int seg = nblk >> 3;      // nblk is a multiple of 8
    const int b0  = sl * seg;
    float a0=0.f,a1=0.f,a2=0.f,a3=0.f,a4=0.f,a5=0.f,a6=0.f,a7=0.f;
    int i = 0;
    for (; i + 8 <= seg; i += 8) {
        const float* pp = partials + (size_t)(b0 + i) * 128 + oh;
        a0 += pp[0*128]; a1 += pp[1*128]; a2 += pp[2*128]; a3 += pp[3*128];
        a4 += pp[4*128]; a5 += pp[5*128]; a6 += pp[6*128]; a7 += pp[7*128];
    }
    for (; i < seg; ++i) a0 += partials[(size_t)(b0 + i) * 128 + oh];
    sh[t] = ((a0+a1)+(a2+a3)) + ((a4+a5)+(a6+a7));
    __syncthreads();

    if (t < 128) {
        float s = 0.0f;
        #pragma unroll
        for (int s2 = 0; s2 < 8; ++s2) s += sh[t + 128*s2];
        cm[t] = s / (float)P;
    }

    // rel-bias mean, closed form per bin; idx(p)=clamp(a+p,0,128), a=pos-P+64
    if (t < 512) {
        const int c = t >> 8, j = t & 255;
        double v = 0.0;
        if (j <= 128) {
            const long long pos = (long long)(*posp);
            const long long a = pos - (long long)P + 64;
            double cnt;
            if (j == 0) {
                long long hi = -a; if (hi > (long long)P - 1) hi = (long long)P - 1;
                cnt = (hi >= 0) ? (double)(hi + 1) : 0.0;
            } else if (j == 128) {
                long long lo = 128 - a; if (lo < 0) lo = 0;
                cnt = (lo <= (long long)P - 1) ? (double)((long long)P - lo) : 0.0;
            } else {
                long long p = (long long)j - a;
                cnt = (p >= 0 && p < (long long)P) ? 1.0 : 0.0;
            }
            v = cnt * (double)rel_bias[2*j + c];
        }
        db[t] = v;
    }
    __syncthreads();
    #pragma unroll
    for (int s = 128; s >= 1; s >>= 1) {
        if (t < 512 && (t & 255) < s) db[t] += db[t + s];
        __syncthreads();
    }
    if (t < 2) bm[t] = (float)(db[t << 8] / (double)P);
    __syncthreads();

    if (t < 32) {
        const float* wr = out_w + t * 128;
        float o0 = out_b[t], o1 = 0.f, o2 = 0.f, o3 = 0.f;
        #pragma unroll
        for (int j = 0; j < 128; j += 4) {
            o0 = fmaf(wr[j+0], cm[j+0], o0);
            o1 = fmaf(wr[j+1], cm[j+1], o1);
            o2 = fmaf(wr[j+2], cm[j+2], o2);
            o3 = fmaf(wr[j+3], cm[j+3], o3);
        }
        outv[t] = (o0+o1) + (o2+o3);
    }
    __syncthreads();

    if (t < 32) {
        float zt = tanh_fast(cand[t] + COUPLING * (outv[t] + bm[t & 1]));
        float other = __shfl_xor(zt, 1, 64);
        float m = fmaf(zt, zt, other * other);
        #pragma unroll
        for (int off = 2; off < 32; off <<= 1) m = fmaxf(m, __shfl_xor(m, off, 64));
        float scale = norm_scale[0] / sqrtf(m + EPSV);
        out[t] = (m > 0.0f) ? zt * scale : zt;
    }
}

extern "C" void kernel_launch(void* const* d_in, const int* in_sizes, int n_in,
                              void* d_out, int out_size, void* d_ws, size_t ws_size,
                              hipStream_t stream)
{
    const float* cand       = (const float*)d_in[0];
    const float* z_past     = (const float*)d_in[1];
    const float* heads_w    = (const float*)d_in[2];
    const float* heads_b    = (const float*)d_in[3];
    const float* out_w      = (const float*)d_in[4];
    const float* out_b      = (const float*)d_in[5];
    const float* rel_bias   = (const float*)d_in[6];
    const float* norm_scale = (const float*)d_in[7];
    const int*   posp       = (const int*)d_in[8];

    const int P = in_sizes[1] / 32;

    int nblk = 1024;                              // 4 blocks/CU (reg-capped anyway)
    size_t need = ((size_t)nblk * 128 + 128) * sizeof(float) + 128 * 32 * sizeof(short);
    if (need > ws_size) {
        nblk = (int)((ws_size - 128 * sizeof(float) - 128 * 32 * sizeof(short))
                     / (128 * sizeof(float)));
        nblk &= ~7;
        if (nblk < 8) nblk = 8;
    }
    float* partials = (float*)d_ws;
    float* cpre     = partials + (size_t)nblk * 128;
    short* wbf      = (short*)(cpre + 128);

    phot_prep<<<1, 128, 0, stream>>>(heads_w, heads_b, cand, cpre, wbf);
    phot_main<<<nblk, 256, 0, stream>>>(z_past, wbf, cpre, partials, P, nblk * 4);
    phot_finalize<<<1, 1024, 0, stream>>>(partials, nblk, P, out_w, out_b,
                                          rel_bias, cand, norm_scale, posp,
                                          (float*)d_out);
}

// Round 3
// 42.814 us; speedup vs baseline: 1.4726x; 1.0667x over previous
//
#include <hip/hip_runtime.h>
#include <hip/hip_bf16.h>
#include <math.h>

#define COUPLING 0.12f
#define EPSV 1e-8f
#define SCALE2L2E 2.8853900817779268f   // 2*log2(e): folds tanh's 2x and exp->exp2

typedef __attribute__((ext_vector_type(8))) short bf16x8;
typedef __attribute__((ext_vector_type(4))) float f32x4;

// tanh(x) from y = 2x*log2(e):  tanh = 1 - 2/(1+2^y). Inf-safe both ways.
__device__ __forceinline__ float tanh_from_e2(float y) {
    float e = __builtin_amdgcn_exp2f(y);
    float r = __builtin_amdgcn_rcpf(1.0f + e);
    return fmaf(-2.0f, r, 1.0f);
}
__device__ __forceinline__ float tanh_fast(float x) {
    return tanh_from_e2(SCALE2L2E * x);
}
// sigma(y) = 1/(1+2^y); tanh = 1 - 2*sigma. Accumulate sigma, fix up with
// valid-row count N at reduction: sum(tanh) = N - 2*sum(sigma).
__device__ __forceinline__ float sig_e2(float y) {
    float e = __builtin_amdgcn_exp2f(y);
    return __builtin_amdgcn_rcpf(1.0f + e);
}

__device__ __forceinline__ short f2bf(float f) {
    __hip_bfloat16 h = __float2bfloat16(f);
    return __builtin_bit_cast(short, h);
}

// Pre-pass (1 block, 128 threads): per output channel oh,
//   cpre[oh] = SCALE * (heads_b[oh] + cand . heads_w[oh][0:32])   (f32)
//   wbf[oh][k] = bf16(SCALE * heads_w[oh][32+k]), k in [0,32)
__global__ __launch_bounds__(128) void phot_prep(
    const float* __restrict__ heads_w, const float* __restrict__ heads_b,
    const float* __restrict__ cand, float* __restrict__ cpre,
    short* __restrict__ wbf)
{
    const int oh = threadIdx.x;               // 0..127
    const float* wr = heads_w + (size_t)oh * 64;
    float s0 = heads_b[oh], s1 = 0.f, s2 = 0.f, s3 = 0.f;
    #pragma unroll
    for (int k = 0; k < 32; k += 4) {
        s0 = fmaf(wr[k+0], cand[k+0], s0);
        s1 = fmaf(wr[k+1], cand[k+1], s1);
        s2 = fmaf(wr[k+2], cand[k+2], s2);
        s3 = fmaf(wr[k+3], cand[k+3], s3);
    }
    cpre[oh] = SCALE2L2E * ((s0 + s1) + (s2 + s3));
    short* wo = wbf + (size_t)oh * 32;
    #pragma unroll
    for (int k = 0; k < 32; ++k) wo[k] = f2bf(SCALE2L2E * wr[32 + k]);
}

// Main, round-6 structure (channel-split, 8 waves/SIMD):
//  - Each of the 4 waves owns 2 of the 8 channel groups -> per-thread state
//    ~45 VGPR (bfrag 8 + cp 2 + acc 8 + pre 2 + addr/temps). launch_bounds
//    (256,8) pins the <=64-VGPR class: 8 blocks/CU, 32 waves/CU, no spill.
//    (Rounds 0-2: 8-group waves sat in the (64,128] class WITH scratch spill
//    -> 21.5KB/block scratch writes + L2-thrashed reloads = the 75% stall.)
//  - All 4 waves compute the SAME 16-row tile from a block-shared 1KB bf16
//    LDS tile (f32->bf16 done once by stagers; readers: 1 ds_read_b128, 0 cvt).
//  - Uniform staging pipeline, depth 2: iter k computes tile k, converts+
//    ds_writes tile k+1 (regs loaded last iter), issues float2 loads of tile
//    k+2. One barrier/iter. No inline asm: compiler emits counted waits.
//  - LDS XOR-swizzle chunk = kg ^ ((row>>1)&3) on BOTH write and read sides:
//    2-way bank aliasing (free, m136) instead of 8-way.
// C/D layout: col=lane&15, row=(lane>>4)*4+reg (m89-verified).
__global__ __launch_bounds__(256, 8) void phot_main(
    const float* __restrict__ z_past,   // [P][32] fp32
    const short* __restrict__ wbf,      // [128][32] bf16, pre-scaled
    const float* __restrict__ cpre_g,   // [128] f32, pre-scaled
    float* __restrict__ partials,       // [NB][128]
    int P, int NB)                      // NB = grid size
{
    __shared__ float wacc[128];
    __shared__ __align__(16) unsigned short zb[2][512];   // 2 x 1KB bf16 tile

    const int tid  = threadIdx.x;
    const int lane = tid & 63;
    const int wv   = tid >> 6;
    const int col  = lane & 15;   // A-row / B-col / C-col
    const int kg   = lane >> 4;   // k-group (k = kg*8 + e)

    // This wave's 2 channel groups.
    const int g0 = wv * 2, g1 = g0 + 1;
    const bf16x8 bfA = *(const bf16x8*)(wbf + (size_t)(g0 * 16 + col) * 32 + kg * 8);
    const bf16x8 bfB = *(const bf16x8*)(wbf + (size_t)(g1 * 16 + col) * 32 + kg * 8);
    const float  cpA = cpre_g[g0 * 16 + col];
    const float  cpB = cpre_g[g1 * 16 + col];

    f32x4 accA = {0,0,0,0}, accB = {0,0,0,0};

    const int T  = (P + 15) >> 4;             // total 16-row tiles
    const int Tf = P >> 4;                    // full tiles
    const int b  = blockIdx.x;
    const int K  = (b < T) ? ((T - 1 - b) / NB + 1) : 0;   // tiles for this block

    // Reader: lane (col,kg) reads 16B chunk (row=col, kg), XOR-swizzled.
    const int a_off = col * 64 + ((kg ^ ((col >> 1) & 3)) << 4);

    // Stager: this thread covers floats f0,f0+1 of each 512-float tile.
    const int f0   = (wv << 7) + (lane << 1);
    const int srow = f0 >> 5;                 // tile row 0..15
    const int scol = f0 & 31;                 // column 0..31 (even)
    const int w_off = srow * 64 + ((((scol >> 3) ^ ((srow >> 1) & 3))) << 4)
                    + ((scol & 7) << 1);

    float2 pre;
    #define SLOAD(tt) { \
        int tc = (tt); if (tc > T - 1) tc = T - 1; \
        int grow = tc * 16 + srow; if (grow > P - 1) grow = P - 1; \
        pre = *(const float2*)(z_past + (size_t)grow * 32 + scol); }
    #define SWRITE(bi) { \
        unsigned int pk = ((unsigned int)(unsigned short)f2bf(pre.y) << 16) | \
                          (unsigned int)(unsigned short)f2bf(pre.x); \
        *(unsigned int*)((char*)&zb[(bi)][0] + w_off) = pk; }

    if (K > 0) {
        SLOAD(b);                 // tile 0
        SWRITE(0);                // (compiler inserts vmcnt wait before cvt)
        SLOAD(b + NB);            // tile 1 -> regs
        __syncthreads();

        for (int k = 0; k < K; ++k) {
            const int tt = b + k * NB;
            const bf16x8 a = *(const bf16x8*)((const char*)&zb[k & 1][0] + a_off);

            if (k + 1 < K) SWRITE((k + 1) & 1);   // publish tile k+1
            SLOAD(b + (k + 2) * NB);              // issue tile k+2 (clamped)

            const int base = tt * 16;
            if (base + 16 <= P) {
                f32x4 c = {cpA, cpA, cpA, cpA};
                f32x4 d = __builtin_amdgcn_mfma_f32_16x16x32_bf16(a, bfA, c, 0, 0, 0);
                accA[0] += sig_e2(d[0]); accA[1] += sig_e2(d[1]);
                accA[2] += sig_e2(d[2]); accA[3] += sig_e2(d[3]);
                c = {cpB, cpB, cpB, cpB};
                d = __builtin_amdgcn_mfma_f32_16x16x32_bf16(a, bfB, c, 0, 0, 0);
                accB[0] += sig_e2(d[0]); accB[1] += sig_e2(d[1]);
                accB[2] += sig_e2(d[2]); accB[3] += sig_e2(d[3]);
            } else {
                const int r0 = base + kg * 4;   // partial tail tile
                f32x4 c = {cpA, cpA, cpA, cpA};
                f32x4 d = __builtin_amdgcn_mfma_f32_16x16x32_bf16(a, bfA, c, 0, 0, 0);
                if (r0 + 0 < P) accA[0] += sig_e2(d[0]);
                if (r0 + 1 < P) accA[1] += sig_e2(d[1]);
                if (r0 + 2 < P) accA[2] += sig_e2(d[2]);
                if (r0 + 3 < P) accA[3] += sig_e2(d[3]);
                c = {cpB, cpB, cpB, cpB};
                d = __builtin_amdgcn_mfma_f32_16x16x32_bf16(a, bfB, c, 0, 0, 0);
                if (r0 + 0 < P) accB[0] += sig_e2(d[0]);
                if (r0 + 1 < P) accB[1] += sig_e2(d[1]);
                if (r0 + 2 < P) accB[2] += sig_e2(d[2]);
                if (r0 + 3 < P) accB[3] += sig_e2(d[3]);
            }
            __syncthreads();
        }
    }
    #undef SLOAD
    #undef SWRITE

    // Per-lane valid-row count (analytic; every wave saw every tile of block b).
    float nsum = 0.0f;
    if (K > 0) {
        int nfull = (b < Tf) ? ((Tf - 1 - b) / NB + 1) : 0;
        nsum = 4.0f * (float)nfull;
        if (Tf < T && b <= Tf && ((Tf - b) % NB) == 0) {   // block owns partial tile
            int prem = P - Tf * 16;
            int nv = prem - kg * 4; if (nv < 0) nv = 0; if (nv > 4) nv = 4;
            nsum += (float)nv;
        }
    }

    // sum(tanh) = nsum - 2*sum(sigma); fold 4 row-regs, then 4 k-groups.
    float sA = nsum - 2.0f * ((accA[0] + accA[1]) + (accA[2] + accA[3]));
    sA += __shfl_xor(sA, 16, 64);
    sA += __shfl_xor(sA, 32, 64);
    float sB = nsum - 2.0f * ((accB[0] + accB[1]) + (accB[2] + accB[3]));
    sB += __shfl_xor(sB, 16, 64);
    sB += __shfl_xor(sB, 32, 64);
    if (lane < 16) {
        wacc[g0 * 16 + lane] = sA;
        wacc[g1 * 16 + lane] = sB;
    }
    __syncthreads();
    if (tid < 128) {
        partials[(size_t)b * 128 + tid] = wacc[tid];
    }
}

// Finalize (validated in rounds 1-2).
__global__ __launch_bounds__(1024) void phot_finalize(
    const float* __restrict__ partials, int nblk, int P,
    const float* __restrict__ out_w,      // [32][128]
    const float* __restrict__ out_b,      // [32]
    const float* __restrict__ rel_bias,   // [129][2]
    const float* __restrict__ cand,       // [32]
    const float* __restrict__ norm_scale, // [1]
    const int* __restrict__ posp,         // [1]
    float* __restrict__ out)              // [32]
{
    __shared__ float  sh[1024];
    __shared__ float  cm[128];
    __shared__ float  outv[32];
    __shared__ double db[512];
    __shared__ float  bm[2];

    const int t  = threadIdx.x;
    const int oh = t & 127;
    const int sl = t >> 7;          // 0..7 slices over blocks

    const int seg = nblk >> 3;      // nblk is a multiple of 8
    const int b0  = sl * seg;
    float a0=0.f,a1=0.f,a2=0.f,a3=0.f,a4=0.f,a5=0.f,a6=0.f,a7=0.f;
    int i = 0;
    for (; i + 8 <= seg; i += 8) {
        const float* pp = partials + (size_t)(b0 + i) * 128 + oh;
        a0 += pp[0*128]; a1 += pp[1*128]; a2 += pp[2*128]; a3 += pp[3*128];
        a4 += pp[4*128]; a5 += pp[5*128]; a6 += pp[6*128]; a7 += pp[7*128];
    }
    for (; i < seg; ++i) a0 += partials[(size_t)(b0 + i) * 128 + oh];
    sh[t] = ((a0+a1)+(a2+a3)) + ((a4+a5)+(a6+a7));
    __syncthreads();

    if (t < 128) {
        float s = 0.0f;
        #pragma unroll
        for (int s2 = 0; s2 < 8; ++s2) s += sh[t + 128*s2];
        cm[t] = s / (float)P;
    }

    // rel-bias mean, closed form per bin; idx(p)=clamp(a+p,0,128), a=pos-P+64
    if (t < 512) {
        const int c = t >> 8, j = t & 255;
        double v = 0.0;
        if (j <= 128) {
            const long long pos = (long long)(*posp);
            const long long a = pos - (long long)P + 64;
            double cnt;
            if (j == 0) {
                long long hi = -a; if (hi > (long long)P - 1) hi = (long long)P - 1;
                cnt = (hi >= 0) ? (double)(hi + 1) : 0.0;
            } else if (j == 128) {
                long long lo = 128 - a; if (lo < 0) lo = 0;
                cnt = (lo <= (long long)P - 1) ? (double)((long long)P - lo) : 0.0;
            } else {
                long long p = (long long)j - a;
                cnt = (p >= 0 && p < (long long)P) ? 1.0 : 0.0;
            }
            v = cnt * (double)rel_bias[2*j + c];
        }
        db[t] = v;
    }
    __syncthreads();
    #pragma unroll
    for (int s = 128; s >= 1; s >>= 1) {
        if (t < 512 && (t & 255) < s) db[t] += db[t + s];
        __syncthreads();
    }
    if (t < 2) bm[t] = (float)(db[t << 8] / (double)P);
    __syncthreads();

    if (t < 32) {
        const float* wr = out_w + t * 128;
        float o0 = out_b[t], o1 = 0.f, o2 = 0.f, o3 = 0.f;
        #pragma unroll
        for (int j = 0; j < 128; j += 4) {
            o0 = fmaf(wr[j+0], cm[j+0], o0);
            o1 = fmaf(wr[j+1], cm[j+1], o1);
            o2 = fmaf(wr[j+2], cm[j+2], o2);
            o3 = fmaf(wr[j+3], cm[j+3], o3);
        }
        outv[t] = (o0+o1) + (o2+o3);
    }
    __syncthreads();

    if (t < 32) {
        float zt = tanh_fast(cand[t] + COUPLING * (outv[t] + bm[t & 1]));
        float other = __shfl_xor(zt, 1, 64);
        float m = fmaf(zt, zt, other * other);
        #pragma unroll
        for (int off = 2; off < 32; off <<= 1) m = fmaxf(m, __shfl_xor(m, off, 64));
        float scale = norm_scale[0] / sqrtf(m + EPSV);
        out[t] = (m > 0.0f) ? zt * scale : zt;
    }
}

extern "C" void kernel_launch(void* const* d_in, const int* in_sizes, int n_in,
                              void* d_out, int out_size, void* d_ws, size_t ws_size,
                              hipStream_t stream)
{
    const float* cand       = (const float*)d_in[0];
    const float* z_past     = (const float*)d_in[1];
    const float* heads_w    = (const float*)d_in[2];
    const float* heads_b    = (const float*)d_in[3];
    const float* out_w      = (const float*)d_in[4];
    const float* out_b      = (const float*)d_in[5];
    const float* rel_bias   = (const float*)d_in[6];
    const float* norm_scale = (const float*)d_in[7];
    const int*   posp       = (const int*)d_in[8];

    const int P = in_sizes[1] / 32;

    int nblk = 2048;                              // 8 blocks/CU, 32 waves/CU
    size_t need = ((size_t)nblk * 128 + 128) * sizeof(float) + 128 * 32 * sizeof(short);
    if (need > ws_size) {
        nblk = (int)((ws_size - 128 * sizeof(float) - 128 * 32 * sizeof(short))
                     / (128 * sizeof(float)));
        nblk &= ~7;
        if (nblk < 8) nblk = 8;
    }
    float* partials = (float*)d_ws;
    float* cpre     = partials + (size_t)nblk * 128;
    short* wbf      = (short*)(cpre + 128);

    phot_prep<<<1, 128, 0, stream>>>(heads_w, heads_b, cand, cpre, wbf);
    phot_main<<<nblk, 256, 0, stream>>>(z_past, wbf, cpre, partials, P, nblk);
    phot_finalize<<<1, 1024, 0, stream>>>(partials, nblk, P, out_w, out_b,
                                          rel_bias, cand, norm_scale, posp,
                                          (float*)d_out);
}

// Round 4
// 39.004 us; speedup vs baseline: 1.6165x; 1.0977x over previous
//
#include <hip/hip_runtime.h>
#include <hip/hip_bf16.h>
#include <math.h>

#define COUPLING 0.12f
#define EPSV 1e-8f
#define SCALE2L2E 2.8853900817779268f   // 2*log2(e): folds tanh's 2x and exp->exp2

typedef __attribute__((ext_vector_type(8))) short bf16x8;
typedef __attribute__((ext_vector_type(4))) float f32x4;

// tanh(x) from y = 2x*log2(e):  tanh = 1 - 2/(1+2^y). Inf-safe both ways.
__device__ __forceinline__ float tanh_from_e2(float y) {
    float e = __builtin_amdgcn_exp2f(y);
    float r = __builtin_amdgcn_rcpf(1.0f + e);
    return fmaf(-2.0f, r, 1.0f);
}
__device__ __forceinline__ float tanh_fast(float x) {
    return tanh_from_e2(SCALE2L2E * x);
}
// sigma(y) = 1/(1+2^y); tanh = 1 - 2*sigma. Accumulate sigma, fix up with
// valid-row count N at reduction: sum(tanh) = N - 2*sum(sigma).
__device__ __forceinline__ float sig_e2(float y) {
    float e = __builtin_amdgcn_exp2f(y);
    return __builtin_amdgcn_rcpf(1.0f + e);
}

__device__ __forceinline__ short f2bf(float f) {
    __hip_bfloat16 h = __float2bfloat16(f);
    return __builtin_bit_cast(short, h);
}

// Pre-pass (1 block, 128 threads): per output channel oh,
//   cpre[oh] = SCALE * (heads_b[oh] + cand . heads_w[oh][0:32])   (f32)
//   wbf[oh][k] = bf16(SCALE * heads_w[oh][32+k]), k in [0,32)
__global__ __launch_bounds__(128) void phot_prep(
    const float* __restrict__ heads_w, const float* __restrict__ heads_b,
    const float* __restrict__ cand, float* __restrict__ cpre,
    short* __restrict__ wbf)
{
    const int oh = threadIdx.x;               // 0..127
    const float* wr = heads_w + (size_t)oh * 64;
    float s0 = heads_b[oh], s1 = 0.f, s2 = 0.f, s3 = 0.f;
    #pragma unroll
    for (int k = 0; k < 32; k += 4) {
        s0 = fmaf(wr[k+0], cand[k+0], s0);
        s1 = fmaf(wr[k+1], cand[k+1], s1);
        s2 = fmaf(wr[k+2], cand[k+2], s2);
        s3 = fmaf(wr[k+3], cand[k+3], s3);
    }
    cpre[oh] = SCALE2L2E * ((s0 + s1) + (s2 + s3));
    short* wo = wbf + (size_t)oh * 32;
    #pragma unroll
    for (int k = 0; k < 32; ++k) wo[k] = f2bf(SCALE2L2E * wr[32 + k]);
}

// Main, round-7 structure: phased pipeline with RAW barriers.
// Root cause of rounds 0-3 (~2 TB/s plateau): __syncthreads() compiles to
// "s_waitcnt vmcnt(0) lgkmcnt(0); s_barrier" -- every iteration drained the
// JUST-ISSUED prefetch loads, exposing full HBM latency per tile (~2 us/iter,
// phase-locked across 2048 blocks). Fix:
//  - Phases of 4 tiles; LDS ring of 3 phase-slots (3 x 4 x 1KB bf16 = 12KB).
//  - Per phase, wave wv reg-stages ITS tile (2 x float4 -> preA/preB), the
//    data is ds_written (cvt to bf16 once) at phase+1 and read at phase+2.
//    The ONLY vmcnt waits are compiler-counted waits on preA/preB whose loads
//    are a full phase old. Barriers are raw s_barrier + manual lgkmcnt(0) --
//    prefetch loads stay in flight across barriers (T3/T4, m201 template).
//  - Channel-split: each wave owns 2 of 8 channel groups (VGPR ~46 ->
//    true 8 waves/SIMD with launch_bounds(256,8); 12.5KB LDS -> 8 blocks/CU).
//  - Chunk XOR-swizzle (slot = chunk ^ (row&3)) on write and read sides:
//    both ds_write_b128 and ds_read_b128 are uniform 8-lanes-per-4-bank
//    groups = conflict-free minimum.
// C/D layout: col=lane&15, row=(lane>>4)*4+reg (m89-verified).
__global__ __launch_bounds__(256, 8) void phot_main(
    const float* __restrict__ z_past,   // [P][32] fp32
    const short* __restrict__ wbf,      // [128][32] bf16, pre-scaled
    const float* __restrict__ cpre_g,   // [128] f32, pre-scaled
    float* __restrict__ partials,       // [NB][128]
    int P, int NB)                      // NB = grid size
{
    __shared__ float wacc[128];
    __shared__ __align__(16) unsigned short zb[3][4][512];  // [slot][tile][16x32 bf16]

    const int tid  = threadIdx.x;
    const int lane = tid & 63;
    const int wv   = tid >> 6;
    const int col  = lane & 15;   // A-row / B-col / C-col
    const int kg   = lane >> 4;   // k-group (k = kg*8 + e)

    // This wave's 2 channel groups.
    const int g0 = wv * 2, g1 = g0 + 1;
    const bf16x8 bfA = *(const bf16x8*)(wbf + (size_t)(g0 * 16 + col) * 32 + kg * 8);
    const bf16x8 bfB = *(const bf16x8*)(wbf + (size_t)(g1 * 16 + col) * 32 + kg * 8);
    const float  cpA = cpre_g[g0 * 16 + col];
    const float  cpB = cpre_g[g1 * 16 + col];

    f32x4 accA = {0,0,0,0}, accB = {0,0,0,0};

    const int T  = (P + 15) >> 4;             // total 16-row tiles
    const int Tf = P >> 4;                    // full tiles
    const int b  = blockIdx.x;
    const int K  = (b < T) ? ((T - 1 - b) / NB + 1) : 0;   // tiles for this block
    const int PH = (K + 3) >> 2;              // phases of 4 tiles

    // Stager lane mapping: lane covers tile floats [sr*32 + sc*8, +8).
    const int sr = lane >> 2;                 // row 0..15
    const int sc = lane & 3;                  // chunk 0..3 (8 floats = 16B bf16)
    const int woff = sr * 32 + ((sc ^ (sr & 3)) << 3);   // ushort offset in tile

    // Reader offset: row=col, chunk=kg, swizzled slot.
    const int roff = col * 32 + ((kg ^ (col & 3)) << 3); // ushort offset in tile

    f32x4 preA, preB;

    // Load this wave's tile of phase ph into pre regs (2x global_load_dwordx4).
    #define SLOADP(ph) { \
        const int j_ = 4 * (ph) + wv; \
        if (j_ < K) { \
            const int tt_ = b + j_ * NB; \
            int grow = tt_ * 16 + sr; if (grow > P - 1) grow = P - 1; \
            const float* g_ = z_past + (size_t)grow * 32 + sc * 8; \
            preA = *(const f32x4*)g_; \
            preB = *(const f32x4*)(g_ + 4); \
        } }
    // Convert + publish pre regs into ring slot (ph)%3 (compiler inserts the
    // counted vmcnt for preA/preB -- the only outstanding vmem ops).
    #define SWRITEP(ph) { \
        const int j_ = 4 * (ph) + wv; \
        if (j_ < K) { \
            bf16x8 w_; \
            w_[0]=f2bf(preA[0]); w_[1]=f2bf(preA[1]); w_[2]=f2bf(preA[2]); w_[3]=f2bf(preA[3]); \
            w_[4]=f2bf(preB[0]); w_[5]=f2bf(preB[1]); w_[6]=f2bf(preB[2]); w_[7]=f2bf(preB[3]); \
            *(bf16x8*)(&zb[(ph) % 3][wv][woff]) = w_; \
        } }
    // Compute tile j of phase p from ring slot p%3.
    #define CTILE(p, j) { \
        const int jj_ = 4 * (p) + (j); \
        if (jj_ < K) { \
            const int tt_ = b + jj_ * NB; \
            const bf16x8 a_ = *(const bf16x8*)(&zb[(p) % 3][j][roff]); \
            const int base_ = tt_ * 16; \
            if (base_ + 16 <= P) { \
                f32x4 c_ = {cpA, cpA, cpA, cpA}; \
                f32x4 d_ = __builtin_amdgcn_mfma_f32_16x16x32_bf16(a_, bfA, c_, 0, 0, 0); \
                accA[0] += sig_e2(d_[0]); accA[1] += sig_e2(d_[1]); \
                accA[2] += sig_e2(d_[2]); accA[3] += sig_e2(d_[3]); \
                c_ = {cpB, cpB, cpB, cpB}; \
                d_ = __builtin_amdgcn_mfma_f32_16x16x32_bf16(a_, bfB, c_, 0, 0, 0); \
                accB[0] += sig_e2(d_[0]); accB[1] += sig_e2(d_[1]); \
                accB[2] += sig_e2(d_[2]); accB[3] += sig_e2(d_[3]); \
            } else { \
                const int r0_ = base_ + kg * 4; \
                f32x4 c_ = {cpA, cpA, cpA, cpA}; \
                f32x4 d_ = __builtin_amdgcn_mfma_f32_16x16x32_bf16(a_, bfA, c_, 0, 0, 0); \
                if (r0_ + 0 < P) accA[0] += sig_e2(d_[0]); \
                if (r0_ + 1 < P) accA[1] += sig_e2(d_[1]); \
                if (r0_ + 2 < P) accA[2] += sig_e2(d_[2]); \
                if (r0_ + 3 < P) accA[3] += sig_e2(d_[3]); \
                c_ = {cpB, cpB, cpB, cpB}; \
                d_ = __builtin_amdgcn_mfma_f32_16x16x32_bf16(a_, bfB, c_, 0, 0, 0); \
                if (r0_ + 0 < P) accB[0] += sig_e2(d_[0]); \
                if (r0_ + 1 < P) accB[1] += sig_e2(d_[1]); \
                if (r0_ + 2 < P) accB[2] += sig_e2(d_[2]); \
                if (r0_ + 3 < P) accB[3] += sig_e2(d_[3]); \
            } \
        } }

    if (K > 0) {
        SLOADP(0);
        SWRITEP(0);               // counted vmcnt wait (prologue, once)
        SLOADP(1);
        asm volatile("s_waitcnt lgkmcnt(0)" ::: "memory");
        __builtin_amdgcn_s_barrier();

        for (int p = 0; p < PH; ++p) {
            if (p + 1 < PH) SWRITEP(p + 1);   // publish next phase (pre is a phase old)
            if (p + 2 < PH) SLOADP(p + 2);    // issue loads 2 phases ahead
            CTILE(p, 0); CTILE(p, 1); CTILE(p, 2); CTILE(p, 3);
            asm volatile("s_waitcnt lgkmcnt(0)" ::: "memory");
            __builtin_amdgcn_s_barrier();     // RAW barrier: vmem stays in flight
        }
    }
    #undef SLOADP
    #undef SWRITEP
    #undef CTILE

    // Per-lane valid-row count (analytic; every wave saw every tile of block b).
    float nsum = 0.0f;
    if (K > 0) {
        int nfull = (b < Tf) ? ((Tf - 1 - b) / NB + 1) : 0;
        nsum = 4.0f * (float)nfull;
        if (Tf < T && b <= Tf && ((Tf - b) % NB) == 0) {   // block owns partial tile
            int prem = P - Tf * 16;
            int nv = prem - kg * 4; if (nv < 0) nv = 0; if (nv > 4) nv = 4;
            nsum += (float)nv;
        }
    }

    // sum(tanh) = nsum - 2*sum(sigma); fold 4 row-regs, then 4 k-groups.
    float sA = nsum - 2.0f * ((accA[0] + accA[1]) + (accA[2] + accA[3]));
    sA += __shfl_xor(sA, 16, 64);
    sA += __shfl_xor(sA, 32, 64);
    float sB = nsum - 2.0f * ((accB[0] + accB[1]) + (accB[2] + accB[3]));
    sB += __shfl_xor(sB, 16, 64);
    sB += __shfl_xor(sB, 32, 64);
    if (lane < 16) {
        wacc[g0 * 16 + lane] = sA;
        wacc[g1 * 16 + lane] = sB;
    }
    __syncthreads();
    if (tid < 128) {
        partials[(size_t)b * 128 + tid] = wacc[tid];
    }
}

// Mid-reduce: 128 blocks fold partials[nblk][128] -> mid[128][128] so the
// single-block finalize only streams 64KB (1MB from one CU was ~9us).
__global__ __launch_bounds__(128) void phot_mid(
    const float* __restrict__ partials, float* __restrict__ mid, int nblk)
{
    const int g = blockIdx.x, t = threadIdx.x;
    const int seg = nblk >> 7, rem = nblk & 127;
    const int b0  = g * seg + (g < rem ? g : rem);
    const int cnt = seg + (g < rem ? 1 : 0);
    const float* p0 = partials + (size_t)b0 * 128 + t;
    float s = 0.f;
    for (int i = 0; i < cnt; ++i) s += p0[(size_t)i * 128];
    mid[(size_t)g * 128 + t] = s;
}

// Finalize (validated in rounds 1-2); now fed by mid with nblk=128.
__global__ __launch_bounds__(1024) void phot_finalize(
    const float* __restrict__ partials, int nblk, int P,
    const float* __restrict__ out_w,      // [32][128]
    const float* __restrict__ out_b,      // [32]
    const float* __restrict__ rel_bias,   // [129][2]
    const float* __restrict__ cand,       // [32]
    const float* __restrict__ norm_scale, // [1]
    const int* __restrict__ posp,         // [1]
    float* __restrict__ out)              // [32]
{
    __shared__ float  sh[1024];
    __shared__ float  cm[128];
    __shared__ float  outv[32];
    __shared__ double db[512];
    __shared__ float  bm[2];

    const int t  = threadIdx.x;
    const int oh = t & 127;
    const int sl = t >> 7;          // 0..7 slices over blocks

    const int seg = nblk >> 3;      // nblk is a multiple of 8
    const int b0  = sl * seg;
    float a0=0.f,a1=0.f,a2=0.f,a3=0.f,a4=0.f,a5=0.f,a6=0.f,a7=0.f;
    int i = 0;
    for (; i + 8 <= seg; i += 8) {
        const float* pp = partials + (size_t)(b0 + i) * 128 + oh;
        a0 += pp[0*128]; a1 += pp[1*128]; a2 += pp[2*128]; a3 += pp[3*128];
        a4 += pp[4*128]; a5 += pp[5*128]; a6 += pp[6*128]; a7 += pp[7*128];
    }
    for (; i < seg; ++i) a0 += partials[(size_t)(b0 + i) * 128 + oh];
    sh[t] = ((a0+a1)+(a2+a3)) + ((a4+a5)+(a6+a7));
    __syncthreads();

    if (t < 128) {
        float s = 0.0f;
        #pragma unroll
        for (int s2 = 0; s2 < 8; ++s2) s += sh[t + 128*s2];
        cm[t] = s / (float)P;
    }

    // rel-bias mean, closed form per bin; idx(p)=clamp(a+p,0,128), a=pos-P+64
    if (t < 512) {
        const int c = t >> 8, j = t & 255;
        double v = 0.0;
        if (j <= 128) {
            const long long pos = (long long)(*posp);
            const long long a = pos - (long long)P + 64;
            double cnt;
            if (j == 0) {
                long long hi = -a; if (hi > (long long)P - 1) hi = (long long)P - 1;
                cnt = (hi >= 0) ? (double)(hi + 1) : 0.0;
            } else if (j == 128) {
                long long lo = 128 - a; if (lo < 0) lo = 0;
                cnt = (lo <= (long long)P - 1) ? (double)((long long)P - lo) : 0.0;
            } else {
                long long p = (long long)j - a;
                cnt = (p >= 0 && p < (long long)P) ? 1.0 : 0.0;
            }
            v = cnt * (double)rel_bias[2*j + c];
        }
        db[t] = v;
    }
    __syncthreads();
    #pragma unroll
    for (int s = 128; s >= 1; s >>= 1) {
        if (t < 512 && (t & 255) < s) db[t] += db[t + s];
        __syncthreads();
    }
    if (t < 2) bm[t] = (float)(db[t << 8] / (double)P);
    __syncthreads();

    if (t < 32) {
        const float* wr = out_w + t * 128;
        float o0 = out_b[t], o1 = 0.f, o2 = 0.f, o3 = 0.f;
        #pragma unroll
        for (int j = 0; j < 128; j += 4) {
            o0 = fmaf(wr[j+0], cm[j+0], o0);
            o1 = fmaf(wr[j+1], cm[j+1], o1);
            o2 = fmaf(wr[j+2], cm[j+2], o2);
            o3 = fmaf(wr[j+3], cm[j+3], o3);
        }
        outv[t] = (o0+o1) + (o2+o3);
    }
    __syncthreads();

    if (t < 32) {
        float zt = tanh_fast(cand[t] + COUPLING * (outv[t] + bm[t & 1]));
        float other = __shfl_xor(zt, 1, 64);
        float m = fmaf(zt, zt, other * other);
        #pragma unroll
        for (int off = 2; off < 32; off <<= 1) m = fmaxf(m, __shfl_xor(m, off, 64));
        float scale = norm_scale[0] / sqrtf(m + EPSV);
        out[t] = (m > 0.0f) ? zt * scale : zt;
    }
}

extern "C" void kernel_launch(void* const* d_in, const int* in_sizes, int n_in,
                              void* d_out, int out_size, void* d_ws, size_t ws_size,
                              hipStream_t stream)
{
    const float* cand       = (const float*)d_in[0];
    const float* z_past     = (const float*)d_in[1];
    const float* heads_w    = (const float*)d_in[2];
    const float* heads_b    = (const float*)d_in[3];
    const float* out_w      = (const float*)d_in[4];
    const float* out_b      = (const float*)d_in[5];
    const float* rel_bias   = (const float*)d_in[6];
    const float* norm_scale = (const float*)d_in[7];
    const int*   posp       = (const int*)d_in[8];

    const int P = in_sizes[1] / 32;

    int nblk = 2048;                              // 8 blocks/CU, 32 waves/CU
    size_t need = ((size_t)nblk * 128 + 128 * 128 + 128) * sizeof(float)
                + 128 * 32 * sizeof(short);
    if (need > ws_size) {
        nblk = (int)((ws_size - (128 * 128 + 128) * sizeof(float)
                      - 128 * 32 * sizeof(short)) / (128 * sizeof(float)));
        nblk &= ~7;
        if (nblk < 8) nblk = 8;
    }
    float* partials = (float*)d_ws;
    float* mid      = partials + (size_t)nblk * 128;
    float* cpre     = mid + 128 * 128;
    short* wbf      = (short*)(cpre + 128);

    phot_prep<<<1, 128, 0, stream>>>(heads_w, heads_b, cand, cpre, wbf);
    phot_main<<<nblk, 256, 0, stream>>>(z_past, wbf, cpre, partials, P, nblk);
    phot_mid<<<128, 128, 0, stream>>>(partials, mid, nblk);
    phot_finalize<<<1, 1024, 0, stream>>>(mid, 128, P, out_w, out_b,
                                          rel_bias, cand, norm_scale, posp,
                                          (float*)d_out);
}